// Round 8
// baseline (144.264 us; speedup 1.0000x reference)
//
#include <hip/hip_runtime.h>
#include <math.h>

// Problem constants (B=2, D=512, K=32, H=W=64 -> N=4096)
#define B_DIM 2
#define D_DIM 512
#define K_DIM 32
#define N_DIM 4096

typedef float v2f __attribute__((ext_vector_type(2)));

// packed fp32 FMA, broadcasting src1's LO half to both lanes: d += a * b.lo
__device__ __forceinline__ void pk_bl(v2f& d, v2f a, v2f b) {
    asm("v_pk_fma_f32 %0, %1, %2, %0 op_sel:[0,0,0] op_sel_hi:[1,0,1]"
        : "+v"(d) : "v"(a), "v"(b));
}
// broadcast src1's HI half: d += a * b.hi
__device__ __forceinline__ void pk_bh(v2f& d, v2f a, v2f b) {
    asm("v_pk_fma_f32 %0, %1, %2, %0 op_sel:[0,1,0] op_sel_hi:[1,1,1]"
        : "+v"(d) : "v"(a), "v"(b));
}

// agent-scope grid barrier; all 256 blocks guaranteed co-resident
// (LDS 73.7KB -> <=2 blocks/CU, grid 256 <= capacity 512, so all resident)
__device__ __forceinline__ void gridbar(int* cnt, int target) {
    __syncthreads();
    if (threadIdx.x == 0) {
        __hip_atomic_fetch_add(cnt, 1, __ATOMIC_ACQ_REL, __HIP_MEMORY_SCOPE_AGENT);
        while (__hip_atomic_load(cnt, __ATOMIC_ACQUIRE, __HIP_MEMORY_SCOPE_AGENT) < target)
            __builtin_amdgcn_s_sleep(2);
    }
    __syncthreads();
}

// ---------------------------------------------------------------------------
// K0 prep: A[d,k]=s^2, B2[d,k]=-2 s^2 c, CK[k]=sum_d s^2 c^2; zeroes
// Mv/nsq/cnt1-3 (W[0..135]). Runs BEFORE k_mega (stream order = init fence).
// ---------------------------------------------------------------------------
__global__ __launch_bounds__(256)
void k_prep(const float* __restrict__ CW, const float* __restrict__ SC,
            float* __restrict__ A, float* __restrict__ B2,
            float* __restrict__ CK, float* __restrict__ W)
{
    __shared__ float ckred[8][33];
    const int tid = threadIdx.x;
    const int idx = blockIdx.x * 256 + tid;      // d*32 + k
    const int d = idx >> 5, k = idx & 31;
    float s = SC[idx];
    float c = CW[k * D_DIM + d];
    float a = s * s;
    A[idx]  = a;
    B2[idx] = -2.f * a * c;
    if (blockIdx.x == 0) {
        if (tid < 136) W[tid] = 0.f;             // Mv(64) + nsq(64) + cnts + pad
        const int kk = tid & 31, g = tid >> 5;
        float acc = 0.f;
        for (int dd = g * 64; dd < g * 64 + 64; ++dd) {
            float sv = SC[dd * K_DIM + kk];
            float cv = CW[kk * D_DIM + dd];
            acc = fmaf(sv * sv * cv, cv, acc);
        }
        ckred[g][kk] = acc;
        __syncthreads();
        if (tid < 32) {
            float t = 0.f;
#pragma unroll
            for (int i = 0; i < 8; ++i) t += ckred[i][tid];
            CK[tid] = t;
        }
    }
}

// ---------------------------------------------------------------------------
// K1 MEGA: phase A (dist+softmax+Q+Mv) | sync | phase B (T partials, 2x
// k_tpart assignments) | sync | phase C (z, nsq, normalize, Z).
// grid 256 x 256 thr; LDS union 73,728 B (phase A X-tile is the max).
// ---------------------------------------------------------------------------
__global__ __launch_bounds__(256, 1)
void k_mega(const float* __restrict__ X, const float* __restrict__ CW,
            const float* __restrict__ SC, const float* __restrict__ At,
            const float* __restrict__ Bt, const float* __restrict__ CK,
            float* __restrict__ Qout, float* __restrict__ Z,
            float* __restrict__ W, float* __restrict__ TP)
{
    __shared__ __align__(16) float sm[18432];    // 73,728 B
    float* Mv  = W;
    float* nsq = W + 64;
    int*   cnt = (int*)(W + 128);                // cnt[0..2]
    const int tid = threadIdx.x;
    const int blk = blockIdx.x;

    // ================= Phase A: dist + softmax (32 n per block) ===========
    {
        const int b  = blk >> 7;
        const int n0 = (blk & 127) << 5;
        const float* xsrc = X + (size_t)b * D_DIM * N_DIM + n0;
        // stage X [512 d][32 n], row stride 36
#pragma unroll
        for (int i = 0; i < 16; ++i) {
            int f4 = tid + (i << 8);
            int row = f4 >> 3, col4 = (f4 & 7) << 2;
            *(float4*)(&sm[row * 36 + col4]) =
                *(const float4*)(xsrc + (size_t)row * N_DIM + col4);
        }
        __syncthreads();

        const int ks = tid & 7, ng = (tid >> 3) & 7, dh = tid >> 6;
        const float* ar = At + (dh << 7) * K_DIM + (ks << 2);
        const float* br = Bt + (dh << 7) * K_DIM + (ks << 2);
        const float* xr = &sm[(dh << 7) * 36 + (ng << 2)];
        float acc[4][4];
#pragma unroll
        for (int n = 0; n < 4; ++n)
#pragma unroll
            for (int k = 0; k < 4; ++k) acc[n][k] = 0.f;

#pragma unroll 8
        for (int d = 0; d < 128; ++d) {
            float4 a4 = *(const float4*)(ar + d * K_DIM);
            float4 b4 = *(const float4*)(br + d * K_DIM);
            float4 x4 = *(const float4*)(xr + d * 36);
            float av[4] = {a4.x, a4.y, a4.z, a4.w};
            float bv[4] = {b4.x, b4.y, b4.z, b4.w};
            float xv[4] = {x4.x, x4.y, x4.z, x4.w};
#pragma unroll
            for (int n = 0; n < 4; ++n) {
                const float x  = xv[n];
                const float x2 = x * x;
#pragma unroll
                for (int k = 0; k < 4; ++k)
                    acc[n][k] = fmaf(av[k], x2, fmaf(bv[k], x, acc[n][k]));
            }
        }
        __syncthreads();     // X-tile reads done; reuse sm for partials
        // partials: part[(dh*32 + n)*36 + k], region [0, 4608)
#pragma unroll
        for (int nj = 0; nj < 4; ++nj)
            *(float4*)(&sm[((dh << 5) + (ng << 2) + nj) * 36 + (ks << 2)]) =
                make_float4(acc[nj][0], acc[nj][1], acc[nj][2], acc[nj][3]);
        __syncthreads();

        const int k = tid & 31;
        float qm = 0.f;
#pragma unroll
        for (int h = 0; h < 4; ++h) {
            const int n = (h << 3) + (tid >> 5);
            float dsum = CK[k];
#pragma unroll
            for (int i = 0; i < 4; ++i) dsum += sm[((i << 5) + n) * 36 + k];
            float m = dsum;
#pragma unroll
            for (int mk = 16; mk >= 1; mk >>= 1)
                m = fminf(m, __shfl_xor(m, mk));
            float e = __expf(-0.5f * (dsum - m));
            float ssum = e;
#pragma unroll
            for (int mk = 16; mk >= 1; mk >>= 1)
                ssum += __shfl_xor(ssum, mk);
            float q = __fdividef(e, ssum);
            Qout[((size_t)b * N_DIM + n0 + n) * K_DIM + k] = q;
            qm += q;
        }
        // block Q-mass -> Mv atomics (mred region [4608, 4872), no overlap)
        sm[4608 + (tid >> 5) * 33 + k] = qm;
        __syncthreads();
        if (tid < K_DIM) {
            float t = 0.f;
#pragma unroll
            for (int i = 0; i < 8; ++i) t += sm[4608 + i * 33 + tid];
            atomicAdd(&Mv[b * K_DIM + tid], t);
        }
    }
    gridbar(&cnt[0], 256);

    // ================= Phase B: T partials (2 assignments/block) ==========
    {
        float* Xs   = sm;           // 64*68
        float* Qs   = sm + 4352;    // 64*36
        float* red4 = sm + 6656;    // 4*64*36
        const int nsub = tid >> 5;
        const int dp = tid & 7;
        const int kp = (tid >> 3) & 3;
        const int k0t = kp << 3;
        const int wv = tid >> 6;

        for (int a = 0; a < 2; ++a) {
            const int g  = (blk << 1) | a;
            const int ns = g & 31;
            const int dt = (g >> 5) & 7;
            const int b  = g >> 8;

            v2f acc2[8][4];
#pragma unroll
            for (int i = 0; i < 8; ++i)
#pragma unroll
                for (int j = 0; j < 4; ++j) acc2[i][j] = (v2f)(0.f);

            const float* xsrc = X + ((size_t)b * D_DIM + dt * 64) * N_DIM + ns * 128;
            const float* qsrc = Qout + ((size_t)b * N_DIM + ns * 128) * K_DIM;

            for (int ch = 0; ch < 2; ++ch) {
                __syncthreads();
#pragma unroll
                for (int i = 0; i < 4; ++i) {
                    int flat4 = tid + (i << 8);
                    int row = flat4 >> 4;
                    int c4  = (flat4 & 15) << 2;
                    *(float4*)(&Xs[row * 68 + c4]) =
                        *(const float4*)(xsrc + (size_t)row * N_DIM + (ch << 6) + c4);
                }
#pragma unroll
                for (int i = 0; i < 2; ++i) {
                    int flat4 = tid + (i << 8);
                    int nn = flat4 >> 3;
                    int k4 = (flat4 & 7) << 2;
                    *(float4*)(&Qs[nn * 36 + k4]) =
                        *(const float4*)(qsrc + ((ch << 6) + nn) * K_DIM + k4);
                }
                __syncthreads();
#pragma unroll
                for (int s = 0; s < 2; ++s) {
                    const int nb = (nsub << 3) + (s << 2);
                    float4 xr[8];
#pragma unroll
                    for (int i = 0; i < 8; ++i)
                        xr[i] = *(const float4*)(&Xs[(dp + (i << 3)) * 68 + nb]);
#pragma unroll
                    for (int n = 0; n < 4; ++n) {
                        float4 qa = *(const float4*)(&Qs[(nb + n) * 36 + k0t]);
                        float4 qb = *(const float4*)(&Qs[(nb + n) * 36 + k0t + 4]);
                        v2f q2[4] = {{qa.x, qa.y}, {qa.z, qa.w},
                                     {qb.x, qb.y}, {qb.z, qb.w}};
#pragma unroll
                        for (int i = 0; i < 8; ++i) {
                            v2f xlo = {xr[i].x, xr[i].y};
                            v2f xhi = {xr[i].z, xr[i].w};
                            v2f xb2 = (n < 2) ? xlo : xhi;
                            if ((n & 1) == 0) {
#pragma unroll
                                for (int j = 0; j < 4; ++j) pk_bl(acc2[i][j], q2[j], xb2);
                            } else {
#pragma unroll
                                for (int j = 0; j < 4; ++j) pk_bh(acc2[i][j], q2[j], xb2);
                            }
                        }
                    }
                }
            }
            __syncthreads();
#pragma unroll
            for (int i = 0; i < 8; ++i)
#pragma unroll
                for (int j = 0; j < 4; ++j) {
                    acc2[i][j].x += __shfl_xor(acc2[i][j].x, 32);
                    acc2[i][j].y += __shfl_xor(acc2[i][j].y, 32);
                }
            if ((tid & 32) == 0) {
#pragma unroll
                for (int i = 0; i < 8; ++i) {
                    float* r = &red4[(wv * 64 + dp + (i << 3)) * 36 + k0t];
                    *(float4*)(r)     = make_float4(acc2[i][0].x, acc2[i][0].y,
                                                    acc2[i][1].x, acc2[i][1].y);
                    *(float4*)(r + 4) = make_float4(acc2[i][2].x, acc2[i][2].y,
                                                    acc2[i][3].x, acc2[i][3].y);
                }
            }
            __syncthreads();
            float* dst = TP + (((size_t)ns * 2 + b) * D_DIM + dt * 64) * K_DIM;
#pragma unroll
            for (int e = 0; e < 8; ++e) {
                int flat = tid + (e << 8);
                int dl = flat >> 5;
                int k  = flat & 31;
                float s = red4[(0 * 64 + dl) * 36 + k] + red4[(1 * 64 + dl) * 36 + k]
                        + red4[(2 * 64 + dl) * 36 + k] + red4[(3 * 64 + dl) * 36 + k];
                dst[dl * K_DIM + k] = s;
            }
        }
    }
    gridbar(&cnt[1], 256);

    // ================= Phase C: z, nsq, normalize =========================
    {
        const int b   = blk >> 7;
        const int d0  = (blk & 127) << 2;       // 4 d per block
        const int k   = tid & 31;
        const int dd  = (tid >> 5) & 3;
        const int h   = tid >> 7;
        float t = 0.f;
#pragma unroll
        for (int s = 0; s < 16; ++s) {
            int slab = (h << 4) + s;
            t += TP[(((size_t)slab * B_DIM + b) * D_DIM + d0 + dd) * K_DIM + k];
        }
        sm[((dd << 1) + h) * 33 + k] = t;
        __syncthreads();
        float z = 0.f;
        if (h == 0) {
            float T = sm[(dd << 1) * 33 + k] + sm[((dd << 1) + 1) * 33 + k];
            float m = Mv[b * K_DIM + k];
            float c = CW[k * D_DIM + d0 + dd];
            float s2 = SC[(d0 + dd) * K_DIM + k];
            z = s2 * (__fdividef(T, m) - c);
            sm[300 + dd * 33 + k] = z * z;
        }
        __syncthreads();
        if (tid < K_DIM) {
            float nn = sm[300 + tid] + sm[300 + 33 + tid]
                     + sm[300 + 66 + tid] + sm[300 + 99 + tid];
            atomicAdd(&nsq[b * K_DIM + tid], nn);
        }
        gridbar(&cnt[2], 256);
        if (h == 0) {
            float nv = __hip_atomic_load(&nsq[b * K_DIM + k], __ATOMIC_RELAXED,
                                         __HIP_MEMORY_SCOPE_AGENT);
            Z[((size_t)b * D_DIM + d0 + dd) * K_DIM + k] = z * rsqrtf(nv);
        }
    }
}

extern "C" void kernel_launch(void* const* d_in, const int* in_sizes, int n_in,
                              void* d_out, int out_size, void* d_ws, size_t ws_size,
                              hipStream_t stream)
{
    const float* X  = (const float*)d_in[0];   // [2,512,64,64]
    const float* CW = (const float*)d_in[1];   // [32,512]
    const float* SC = (const float*)d_in[2];   // [512,32]
    float* Z = (float*)d_out;                              // [2,512,32]
    float* Q = (float*)d_out + B_DIM * D_DIM * K_DIM;      // [2,4096,32]

    float* W   = (float*)d_ws;                 // Mv(64) nsq(64) cnt(3) pad
    float* TP  = W + 256;                      // 32*2*512*32 floats (4 MB)
    float* At  = TP + 32 * B_DIM * D_DIM * K_DIM;
    float* Bt  = At + D_DIM * K_DIM;
    float* CKt = Bt + D_DIM * K_DIM;

    k_prep<<< 64, 256, 0, stream>>>(CW, SC, At, Bt, CKt, W);
    k_mega<<<256, 256, 0, stream>>>(X, CW, SC, At, Bt, CKt, Q, Z, W, TP);
}

// Round 9
// 133.560 us; speedup vs baseline: 1.0801x; 1.0801x over previous
//
#include <hip/hip_runtime.h>
#include <math.h>

// Problem constants (B=2, D=512, K=32, H=W=64 -> N=4096)
#define B_DIM 2
#define D_DIM 512
#define K_DIM 32
#define N_DIM 4096

typedef float v2f __attribute__((ext_vector_type(2)));

// packed fp32 FMA, broadcasting src1's LO half to both lanes: d += a * b.lo
__device__ __forceinline__ void pk_bl(v2f& d, v2f a, v2f b) {
    asm("v_pk_fma_f32 %0, %1, %2, %0 op_sel:[0,0,0] op_sel_hi:[1,0,1]"
        : "+v"(d) : "v"(a), "v"(b));
}
// broadcast src1's HI half: d += a * b.hi
__device__ __forceinline__ void pk_bh(v2f& d, v2f a, v2f b) {
    asm("v_pk_fma_f32 %0, %1, %2, %0 op_sel:[0,1,0] op_sel_hi:[1,1,1]"
        : "+v"(d) : "v"(a), "v"(b));
}

// ---------------------------------------------------------------------------
// K0 prep: A[d,k]=s^2, B2[d,k]=-2 s^2 c, CK[k]=sum_d s^2 c^2; zeroes
// nsq/cnt (W[0..135]). grid 64 x 256. (verified R3/R6/R7)
// ---------------------------------------------------------------------------
__global__ __launch_bounds__(256)
void k_prep(const float* __restrict__ CW, const float* __restrict__ SC,
            float* __restrict__ A, float* __restrict__ B2,
            float* __restrict__ CK, float* __restrict__ W)
{
    __shared__ float ckred[8][33];
    const int tid = threadIdx.x;
    const int idx = blockIdx.x * 256 + tid;      // d*32 + k
    const int d = idx >> 5, k = idx & 31;
    float s = SC[idx];
    float c = CW[k * D_DIM + d];
    float a = s * s;
    A[idx]  = a;
    B2[idx] = -2.f * a * c;
    if (blockIdx.x == 0) {
        if (tid < 136) W[tid] = 0.f;             // nsq(64) + cnt + pad
        const int kk = tid & 31, g = tid >> 5;
        float acc = 0.f;
        for (int dd = g * 64; dd < g * 64 + 64; ++dd) {
            float sv = SC[dd * K_DIM + kk];
            float cv = CW[kk * D_DIM + dd];
            acc = fmaf(sv * sv * cv, cv, acc);
        }
        ckred[g][kk] = acc;
        __syncthreads();
        if (tid < 32) {
            float t = 0.f;
#pragma unroll
            for (int i = 0; i < 8; ++i) t += ckred[i][tid];
            CK[tid] = t;
        }
    }
}

// ---------------------------------------------------------------------------
// K1 v5: dist + softmax, ALL-LDS inner loop (no global/scratch in hot path).
// grid = 512 = b(2) x nt(256 tiles of 16 n); block 256 thr; LDS 42.5 KB
// -> 2 blocks/CU co-resident at grid 512 (8 waves/CU).
// Per chunk (4 x 128 d): stage A/B2 [128][33] + X [128][17] into LDS, then
// thread (ks=tid&3 -> 8k, ng=(tid>>2)&3 -> 4n, dh=tid>>4 -> 8d serial):
// 5 x ds_read_b128 per 64 FMA (under the ~85 B/cyc LDS ceiling at 8 waves).
// Partials (16 dh) overlay the dead table region; inline softmax + Mpart.
// ---------------------------------------------------------------------------
__global__ __launch_bounds__(256, 2)
void k_distq(const float* __restrict__ X, const float* __restrict__ At,
             const float* __restrict__ Bt, const float* __restrict__ CK,
             float* __restrict__ Qout, float* __restrict__ Mpart)
{
    __shared__ __align__(16) float sm[10624];    // A[0,4224) B[4224,8448) X[8448,10624)
    float* Al = sm;
    float* Bl = sm + 4224;
    float* Xl = sm + 8448;
    float* part = sm;                            // overlays A+B after last chunk

    const int tid = threadIdx.x;
    const int b  = blockIdx.x >> 8;
    const int n0 = (blockIdx.x & 255) << 4;      // 16 n per block

    const int ks = tid & 3;            // k0 = 8*ks
    const int ng = (tid >> 2) & 3;     // n-base = 4*ng
    const int dh = tid >> 4;           // 0..15, 8 d serial each

    float acc[4][8];
#pragma unroll
    for (int n = 0; n < 4; ++n)
#pragma unroll
        for (int k = 0; k < 8; ++k) acc[n][k] = 0.f;

    const float* xsrc = X + (size_t)b * D_DIM * N_DIM + n0;

    for (int c = 0; c < 4; ++c) {
        __syncthreads();
        // stage tables: 128 rows x 32 k, stride 33 (bank-rotating)
#pragma unroll
        for (int i = 0; i < 4; ++i) {
            int f4 = tid + (i << 8);
            int row = f4 >> 3, c4 = (f4 & 7) << 2;
            *(float4*)(&Al[row * 33 + c4]) =
                *(const float4*)(At + ((c << 7) + row) * K_DIM + c4);
            *(float4*)(&Bl[row * 33 + c4]) =
                *(const float4*)(Bt + ((c << 7) + row) * K_DIM + c4);
        }
        // stage X: 128 rows x 16 n, stride 17
#pragma unroll
        for (int i = 0; i < 2; ++i) {
            int f4 = tid + (i << 8);
            int row = f4 >> 2, c4 = (f4 & 3) << 2;
            *(float4*)(&Xl[row * 17 + c4]) =
                *(const float4*)(xsrc + (size_t)((c << 7) + row) * N_DIM + c4);
        }
        __syncthreads();

        const float* aL = &Al[(dh << 3) * 33 + (ks << 3)];
        const float* bL = &Bl[(dh << 3) * 33 + (ks << 3)];
        const float* xL = &Xl[(dh << 3) * 17 + (ng << 2)];
#pragma unroll
        for (int u = 0; u < 8; ++u) {
            float4 a0 = *(const float4*)(aL + u * 33);
            float4 a1 = *(const float4*)(aL + u * 33 + 4);
            float4 b0 = *(const float4*)(bL + u * 33);
            float4 b1 = *(const float4*)(bL + u * 33 + 4);
            float4 x4 = *(const float4*)(xL + u * 17);
            float av[8] = {a0.x, a0.y, a0.z, a0.w, a1.x, a1.y, a1.z, a1.w};
            float bv[8] = {b0.x, b0.y, b0.z, b0.w, b1.x, b1.y, b1.z, b1.w};
            float xv[4] = {x4.x, x4.y, x4.z, x4.w};
#pragma unroll
            for (int n = 0; n < 4; ++n) {
                const float x  = xv[n];
                const float x2 = x * x;
#pragma unroll
                for (int k = 0; k < 8; ++k)
                    acc[n][k] = fmaf(av[k], x2, fmaf(bv[k], x, acc[n][k]));
            }
        }
    }

    // ---- write 16 dh-partials (overlay table region; all reads done) ----
    __syncthreads();
#pragma unroll
    for (int nn = 0; nn < 4; ++nn) {
        float* r = &part[((dh << 4) + (ng << 2) + nn) * 33 + (ks << 3)];
        *(float4*)(r)     = make_float4(acc[nn][0], acc[nn][1], acc[nn][2], acc[nn][3]);
        *(float4*)(r + 4) = make_float4(acc[nn][4], acc[nn][5], acc[nn][6], acc[nn][7]);
    }
    __syncthreads();

    // ---- reduce 16 dh + CK + softmax over k (32-lane groups), 2 passes ----
    const int k = tid & 31;
    float qm = 0.f;
#pragma unroll
    for (int h = 0; h < 2; ++h) {
        const int n = (tid >> 5) + (h << 3);
        float dsum = CK[k];
#pragma unroll
        for (int i = 0; i < 16; ++i) dsum += part[((i << 4) + n) * 33 + k];
        float m = dsum;
#pragma unroll
        for (int mk = 16; mk >= 1; mk >>= 1)
            m = fminf(m, __shfl_xor(m, mk));
        float e = __expf(-0.5f * (dsum - m));
        float ssum = e;
#pragma unroll
        for (int mk = 16; mk >= 1; mk >>= 1)
            ssum += __shfl_xor(ssum, mk);
        float q = __fdividef(e, ssum);
        Qout[((size_t)b * N_DIM + n0 + n) * K_DIM + k] = q;
        qm += q;
    }
    // block Q-mass (no atomics): mred overlays X region (dead now)
    float* mred = Xl;
    mred[(tid >> 5) * 33 + k] = qm;
    __syncthreads();
    if (tid < K_DIM) {
        float t = 0.f;
#pragma unroll
        for (int i = 0; i < 8; ++i) t += mred[i * 33 + tid];
        Mpart[blockIdx.x * K_DIM + tid] = t;
    }
}

// ---------------------------------------------------------------------------
// K2: T partials. T[b,d,k] = sum_n Q[b,n,k] * X[b,d,n], n split 32 ways.
// grid = 512 = b(2) x dtile(8 of 64 d) x ns(32 of 128 n). (R7 verified core)
// ---------------------------------------------------------------------------
__global__ __launch_bounds__(256, 2)
void k_tpart(const float* __restrict__ X, const float* __restrict__ Qin,
             float* __restrict__ TP)
{
    __shared__ __align__(16) float Xs[64 * 68];
    __shared__ __align__(16) float Qs[64 * 36];
    __shared__ __align__(16) float red4[4 * 64 * 36];

    const int tid = threadIdx.x;
    const int bid = blockIdx.x;
    const int ns = bid & 31;
    const int dt = (bid >> 5) & 7;
    const int b  = bid >> 8;
    const int nsub = tid >> 5;
    const int dp = tid & 7;
    const int kp = (tid >> 3) & 3;
    const int k0t = kp << 3;
    const int wv = tid >> 6;

    v2f acc2[8][4];
#pragma unroll
    for (int i = 0; i < 8; ++i)
#pragma unroll
        for (int j = 0; j < 4; ++j) acc2[i][j] = (v2f)(0.f);

    const float* xsrc = X + ((size_t)b * D_DIM + dt * 64) * N_DIM + ns * 128;
    const float* qsrc = Qin + ((size_t)b * N_DIM + ns * 128) * K_DIM;

    for (int ch = 0; ch < 2; ++ch) {
        __syncthreads();
#pragma unroll
        for (int i = 0; i < 4; ++i) {
            int flat4 = tid + (i << 8);
            int row = flat4 >> 4;
            int c4  = (flat4 & 15) << 2;
            *(float4*)(&Xs[row * 68 + c4]) =
                *(const float4*)(xsrc + (size_t)row * N_DIM + (ch << 6) + c4);
        }
#pragma unroll
        for (int i = 0; i < 2; ++i) {
            int flat4 = tid + (i << 8);
            int nn = flat4 >> 3;
            int k4 = (flat4 & 7) << 2;
            *(float4*)(&Qs[nn * 36 + k4]) =
                *(const float4*)(qsrc + ((ch << 6) + nn) * K_DIM + k4);
        }
        __syncthreads();
#pragma unroll
        for (int s = 0; s < 2; ++s) {
            const int nb = (nsub << 3) + (s << 2);
            float4 xr[8];
#pragma unroll
            for (int i = 0; i < 8; ++i)
                xr[i] = *(const float4*)(&Xs[(dp + (i << 3)) * 68 + nb]);
#pragma unroll
            for (int n = 0; n < 4; ++n) {
                float4 qa = *(const float4*)(&Qs[(nb + n) * 36 + k0t]);
                float4 qb = *(const float4*)(&Qs[(nb + n) * 36 + k0t + 4]);
                v2f q2[4] = {{qa.x, qa.y}, {qa.z, qa.w}, {qb.x, qb.y}, {qb.z, qb.w}};
#pragma unroll
                for (int i = 0; i < 8; ++i) {
                    v2f xlo = {xr[i].x, xr[i].y};
                    v2f xhi = {xr[i].z, xr[i].w};
                    v2f xb2 = (n < 2) ? xlo : xhi;
                    if ((n & 1) == 0) {
#pragma unroll
                        for (int j = 0; j < 4; ++j) pk_bl(acc2[i][j], q2[j], xb2);
                    } else {
#pragma unroll
                        for (int j = 0; j < 4; ++j) pk_bh(acc2[i][j], q2[j], xb2);
                    }
                }
            }
        }
    }
    __syncthreads();
#pragma unroll
    for (int i = 0; i < 8; ++i)
#pragma unroll
        for (int j = 0; j < 4; ++j) {
            acc2[i][j].x += __shfl_xor(acc2[i][j].x, 32);
            acc2[i][j].y += __shfl_xor(acc2[i][j].y, 32);
        }
    if ((tid & 32) == 0) {
#pragma unroll
        for (int i = 0; i < 8; ++i) {
            float* r = &red4[(wv * 64 + dp + (i << 3)) * 36 + k0t];
            *(float4*)(r)     = make_float4(acc2[i][0].x, acc2[i][0].y,
                                            acc2[i][1].x, acc2[i][1].y);
            *(float4*)(r + 4) = make_float4(acc2[i][2].x, acc2[i][2].y,
                                            acc2[i][3].x, acc2[i][3].y);
        }
    }
    __syncthreads();
    float* dst = TP + (((size_t)ns * 2 + b) * D_DIM + dt * 64) * K_DIM;
#pragma unroll
    for (int e = 0; e < 8; ++e) {
        int flat = tid + (e << 8);
        int dl = flat >> 5;
        int k  = flat & 31;
        float s = red4[(0 * 64 + dl) * 36 + k] + red4[(1 * 64 + dl) * 36 + k]
                + red4[(2 * 64 + dl) * 36 + k] + red4[(3 * 64 + dl) * 36 + k];
        dst[dl * K_DIM + k] = s;
    }
}

// ---------------------------------------------------------------------------
// K3 (fused): sum 32 TP slabs, M from 256 Mpart chunks, z in regs, nsq via
// device atomics + co-resident grid sync (128 blocks), Z = z * rsqrt(nsq).
// ---------------------------------------------------------------------------
__global__ __launch_bounds__(256)
void k_zfuse(const float* __restrict__ TP, const float* __restrict__ Mpart,
             const float* __restrict__ CW, const float* __restrict__ SC,
             float* __restrict__ Z, float* __restrict__ nsq, int* __restrict__ cnt)
{
    __shared__ float part[8][33];
    const int tid = threadIdx.x;
    const int b  = blockIdx.x >> 6;
    const int ds = blockIdx.x & 63;
    const int d  = (ds << 3) + (tid >> 5);
    const int k  = tid & 31;
    float sum = 0.f;
#pragma unroll
    for (int ns = 0; ns < 32; ++ns)
        sum += TP[(((size_t)ns * 2 + b) * D_DIM + d) * K_DIM + k];
    float m = 0.f;
#pragma unroll 8
    for (int i = 0; i < 256; ++i)
        m += Mpart[((b << 8) + i) * K_DIM + k];
    float c = CW[k * D_DIM + d];
    float s = SC[d * K_DIM + k];
    float z = s * (__fdividef(sum, m) - c);
    part[tid >> 5][k] = z * z;
    __syncthreads();
    if (tid < K_DIM) {
        float t = 0.f;
#pragma unroll
        for (int i = 0; i < 8; ++i) t += part[i][tid];
        atomicAdd(&nsq[b * K_DIM + tid], t);
    }
    __syncthreads();
    if (tid == 0) {
        __hip_atomic_fetch_add(cnt, 1, __ATOMIC_ACQ_REL, __HIP_MEMORY_SCOPE_AGENT);
        while (__hip_atomic_load(cnt, __ATOMIC_ACQUIRE, __HIP_MEMORY_SCOPE_AGENT) < 128)
            __builtin_amdgcn_s_sleep(1);
    }
    __syncthreads();
    float nv = __hip_atomic_load(&nsq[b * K_DIM + k], __ATOMIC_RELAXED,
                                 __HIP_MEMORY_SCOPE_AGENT);
    Z[((b * D_DIM) + d) * K_DIM + k] = z * rsqrtf(nv);
}

extern "C" void kernel_launch(void* const* d_in, const int* in_sizes, int n_in,
                              void* d_out, int out_size, void* d_ws, size_t ws_size,
                              hipStream_t stream)
{
    const float* X  = (const float*)d_in[0];   // [2,512,64,64]
    const float* CW = (const float*)d_in[1];   // [32,512]
    const float* SC = (const float*)d_in[2];   // [512,32]
    float* Z = (float*)d_out;                              // [2,512,32]
    float* Q = (float*)d_out + B_DIM * D_DIM * K_DIM;      // [2,4096,32]

    float* W    = (float*)d_ws;
    float* nsq  = W;                                       // 64 floats
    int*   cnt  = (int*)(W + 64);                          // 1 int (+pad)
    float* Mpart= W + 128;                                 // 512*32 = 16384
    float* TP   = Mpart + 512 * K_DIM;                     // 4 MB
    float* At   = TP + 32 * B_DIM * D_DIM * K_DIM;         // 16384 floats
    float* Bt   = At + D_DIM * K_DIM;                      // 16384 floats
    float* CKt  = Bt + D_DIM * K_DIM;                      // 32 floats

    k_prep <<< 64, 256, 0, stream>>>(CW, SC, At, Bt, CKt, W);
    k_distq<<<512, 256, 0, stream>>>(X, At, Bt, CKt, Q, Mpart);
    k_tpart<<<512, 256, 0, stream>>>(X, Q, TP);
    k_zfuse<<<128, 256, 0, stream>>>(TP, Mpart, CW, SC, Z, nsq, cnt);
}